// Round 1
// 1786.416 us; speedup vs baseline: 1.8227x; 1.8227x over previous
//
#include <hip/hip_runtime.h>
#include <hip/hip_bf16.h>

#define DIV_UP(a,b) (((a)+(b)-1)/(b))

typedef __attribute__((ext_vector_type(8))) short short8;
typedef __attribute__((ext_vector_type(16))) float floatx16;

__device__ __forceinline__ ushort f2bf(float f) {
    uint u = __builtin_bit_cast(uint, f);
    u += 0x7fffu + ((u >> 16) & 1u);
    return (ushort)(u >> 16);
}
__device__ __forceinline__ uint pk2(float a, float b) {
    union { __hip_bfloat162 h; uint u; } c;
    c.h = __float22bfloat162_rn(make_float2(a, b));
    return c.u;
}

// ---------------------------------------------------------------------------
// conv_k1: implicit-GEMM conv3x3 SAME + bias + ReLU, bf16 MFMA 32x32x16.
//
// Block = 64 Cout x 128 px (16x8 spatial tile), 4 waves; wave w owns px
// subtile [w*32, w*32+32) and computes BOTH 32-co m-tiles (2 MFMA / B-frag).
// K is processed in chunks of 32 ci (chunk K = 9 taps * 32 = 288):
//   - B: 18x10 halo x 32 ci staged once in LDS (pixel-major, ci-contiguous);
//        all 9 taps read from it via shifted pixel address (9x reuse).
//        16B-slot XOR swizzle by (halo_row&3) -> conflict-free ds_read_b128.
//   - A: weights pre-reordered into exact fragment order by wconv_zh;
//        staged global->reg->LDS (coalesced 16B/lane), conflict-free reads.
//   - next chunk's global loads issued after the post-write barrier so they
//     overlap the 18-kstep MFMA section.
// CIN==3 (conv0): single chunk, im2col materialized per-pixel in LDS.
// Halo reads beyond the padded plane are min-clamped (only feed discarded
// output rows/cols; guarded at the store).
// ---------------------------------------------------------------------------
template<int CIN>
__global__ __launch_bounds__(256, 2)
void conv_k1(const float* __restrict__ in, const ushort* __restrict__ wfrag,
             const float* __restrict__ bias, float* __restrict__ out,
             int H, int W, int tw) {
    constexpr bool C3  = (CIN == 3);
    constexpr int NC   = C3 ? 1 : (CIN / 32);   // chunks
    constexpr int KS   = C3 ? 2 : 18;           // 16-k steps per chunk
    constexpr int AB16 = C3 ? 256 : 2304;       // A 16B-blocks per chunk
    constexpr int NA   = AB16 / 256;            // A blocks per thread
    constexpr int NPX  = C3 ? 128 : 180;        // B pixels in LDS
    constexpr int NBI  = C3 ? 4 : 6;            // B stage iters per thread

    __shared__ ushort Asm[AB16 * 8];
    __shared__ ushort Bsm[NPX * 32];

    const int tid  = threadIdx.x;
    const int lane = tid & 63;
    const int wave = __builtin_amdgcn_readfirstlane(tid >> 6);
    const int half = lane >> 5;
    const int l31  = lane & 31;
    const int Wp = W + 2, Hp = H + 2;
    const int plane = Hp * Wp;
    const int Cout = gridDim.y * 64;
    const int w0  = (blockIdx.x % tw) * 8;
    const int h0  = (blockIdx.x / tw) * 16;
    const int co0 = blockIdx.y * 64;
    const int img = blockIdx.z;
    const float* inb = in + (size_t)img * CIN * plane;
    const uint4* A4  = (const uint4*)wfrag + (size_t)blockIdx.y * NC * AB16;

    const int p    = wave * 32 + l31;    // pixel within 128-px tile
    const int prow = p >> 3, pcol = p & 7;

    uint4 aReg[NA];
    float bReg[NBI][4];

    floatx16 acc0 = {0,0,0,0,0,0,0,0,0,0,0,0,0,0,0,0};
    floatx16 acc1 = {0,0,0,0,0,0,0,0,0,0,0,0,0,0,0,0};

    auto stageA = [&](int c) {
#pragma unroll
        for (int j = 0; j < NA; ++j)
            aReg[j] = A4[(size_t)c * AB16 + j * 256 + tid];
    };

    auto stageB = [&](int c) {
        if constexpr (C3) {
            (void)c;
#pragma unroll
            for (int it = 0; it < 4; ++it) {
                int u = it * 256 + tid;
                int px = u >> 3, kq = u & 7;
                int pr = px >> 3, pc = px & 7;
#pragma unroll
                for (int j = 0; j < 4; ++j) {
                    int k = kq * 4 + j;
                    float v = 0.f;
                    if (k < 27) {
                        int tap = k / 3, ci = k - tap * 3;
                        int kh = tap / 3, kw = tap - kh * 3;
                        int rr = min(h0 + pr + kh, Hp - 1);
                        int cc = min(w0 + pc + kw, Wp - 1);
                        v = inb[(size_t)ci * plane + rr * Wp + cc];
                    }
                    bReg[it][j] = v;
                }
            }
        } else {
            const int q = tid >> 5, l5 = tid & 31;
            const float* cbase = inb + (size_t)(c * 32 + q * 4) * plane;
#pragma unroll
            for (int it = 0; it < 6; ++it) {
                int px = it * 32 + l5;
                if (px < 180) {
                    int pr = px / 10, pc = px - pr * 10;
                    int rr = min(h0 + pr, Hp - 1);
                    int cc = min(w0 + pc, Wp - 1);
                    const float* a = cbase + (size_t)rr * Wp + cc;
                    bReg[it][0] = a[0];
                    bReg[it][1] = a[plane];
                    bReg[it][2] = a[2 * plane];
                    bReg[it][3] = a[3 * plane];
                }
            }
        }
    };

    auto writeAB = [&]() {
#pragma unroll
        for (int j = 0; j < NA; ++j)
            *(uint4*)(Asm + (size_t)(j * 256 + tid) * 8) = aReg[j];
        if constexpr (C3) {
#pragma unroll
            for (int it = 0; it < 4; ++it) {
                int u = it * 256 + tid;
                int px = u >> 3, kq = u & 7;
                int sx = (px >> 3) & 3;
                uint2 v;
                v.x = pk2(bReg[it][0], bReg[it][1]);
                v.y = pk2(bReg[it][2], bReg[it][3]);
                *(uint2*)((char*)Bsm + px * 64 + ((kq ^ (sx << 1)) << 3)) = v;
            }
        } else {
            const int q = tid >> 5, l5 = tid & 31;
#pragma unroll
            for (int it = 0; it < 6; ++it) {
                int px = it * 32 + l5;
                if (px < 180) {
                    int sx = (px / 10) & 3;
                    uint2 v;
                    v.x = pk2(bReg[it][0], bReg[it][1]);
                    v.y = pk2(bReg[it][2], bReg[it][3]);
                    *(uint2*)((char*)Bsm + px * 64 + ((q ^ (sx << 1)) << 3)) = v;
                }
            }
        }
    };

    auto compute = [&]() {
#pragma unroll
        for (int ks = 0; ks < KS; ++ks) {
            int boff;
            if constexpr (C3) {
                int slot = (ks & 1) * 2 + half;
                boff = p * 64 + ((slot ^ ((p >> 3) & 3)) << 4);
            } else {
                const int tap = ks >> 1;
                const int kh = tap / 3, kw = tap - kh * 3;
                int hr = prow + kh;
                int hp = hr * 10 + pcol + kw;
                int slot = (ks & 1) * 2 + half;
                boff = hp * 64 + ((slot ^ (hr & 3)) << 4);
            }
            short8 b  = *(const short8*)((const char*)Bsm + boff);
            short8 a0 = *(const short8*)((const char*)Asm +
                          ((((ks * 2 + 0) * 2 + half) * 32 + l31) << 4));
            short8 a1 = *(const short8*)((const char*)Asm +
                          ((((ks * 2 + 1) * 2 + half) * 32 + l31) << 4));
            acc0 = __builtin_amdgcn_mfma_f32_32x32x16_bf16(a0, b, acc0, 0, 0, 0);
            acc1 = __builtin_amdgcn_mfma_f32_32x32x16_bf16(a1, b, acc1, 0, 0, 0);
        }
    };

    stageA(0); stageB(0);
    for (int c = 0; c < NC; ++c) {
        if (c) __syncthreads();          // prev compute done; LDS reusable
        writeAB();                       // (compiler waits stage loads here)
        __syncthreads();                 // LDS visible to all waves
        if (c + 1 < NC) { stageA(c + 1); stageB(c + 1); }  // fly during MFMAs
        compute();
    }

    // epilogue: C/D 32x32 mapping col(n)=lane&31, row(m)=(r&3)+8*(r>>2)+4*half
    const int eh = h0 + prow, ew = w0 + pcol;
    if (eh < H && ew < W) {
        float* ob = out + ((size_t)img * Cout + co0) * plane
                        + (size_t)(eh + 1) * Wp + (ew + 1);
#pragma unroll
        for (int r = 0; r < 16; ++r) {
            int m = (r & 3) + 8 * (r >> 2) + 4 * half;
            float v0 = acc0[r] + bias[co0 + m];
            float v1 = acc1[r] + bias[co0 + 32 + m];
            ob[(size_t)m * plane]        = fmaxf(v0, 0.f);
            ob[(size_t)(m + 32) * plane] = fmaxf(v1, 0.f);
        }
    }
}

// ---------------------------------------------------------------------------
// Weight convert OIHW fp32 -> fragment-ordered bf16, fused with zeroing the
// halo ring of the conv's destination buffer.
// Fragment order (CIN>=32): per (co-block cb, chunk c): 16B-block index
//   blk = ((ks*2+mt)*2+half)*32 + c5 ; k_local = ks*16 + half*8 + i
//   tap = k_local>>5 ; ci = c*32 + (k_local&31) + i ; co = cb*64 + mt*32 + c5
// CIN==3: one chunk, KPAD=32, k = tap*3+ci (k>=27 zero-padded).
// ---------------------------------------------------------------------------
__global__ __launch_bounds__(256)
void wconv_zh(const float* __restrict__ src, ushort* __restrict__ dst,
              int CIN, int Cout, int wblocks,
              float* __restrict__ halo, int planes, int H, int W) {
    int b = blockIdx.x;
    if (b < wblocks) {
        int idx = b * 256 + threadIdx.x;       // global 16B-block index
        ushort v[8];
        if (CIN == 3) {
            if (idx >= 256) return;
            int c5 = idx & 31, r = idx >> 5;
            int half = r & 1, mt = (r >> 1) & 1, ks = r >> 2;
            int co = mt * 32 + c5;
            int kl = ks * 16 + half * 8;
#pragma unroll
            for (int i = 0; i < 8; ++i) {
                int k = kl + i;
                ushort x = 0;
                if (k < 27) {
                    int tap = k / 3, ci = k - tap * 3;
                    x = f2bf(src[(size_t)(co * 3 + ci) * 9 + tap]);
                }
                v[i] = x;
            }
        } else {
            int nblk = Cout * (9 * CIN) / 8;
            if (idx >= nblk) return;
            int NC = CIN >> 5;
            int blk = idx % 2304;
            int cbc = idx / 2304;
            int c = cbc % NC, cb = cbc / NC;
            int c5 = blk & 31, r = blk >> 5;
            int half = r & 1, mt = (r >> 1) & 1, ks = r >> 2;
            int kl = ks * 16 + half * 8;
            int tap = kl >> 5;
            int cibase = c * 32 + (kl & 31);
            int co = cb * 64 + mt * 32 + c5;
            const float* s = src + (size_t)co * CIN * 9 + tap;
#pragma unroll
            for (int i = 0; i < 8; ++i)
                v[i] = f2bf(s[(size_t)(cibase + i) * 9]);
        }
        uint4 o;
        o.x = (uint)v[0] | ((uint)v[1] << 16);
        o.y = (uint)v[2] | ((uint)v[3] << 16);
        o.z = (uint)v[4] | ((uint)v[5] << 16);
        o.w = (uint)v[6] | ((uint)v[7] << 16);
        *(uint4*)(dst + (size_t)idx * 8) = o;
    } else {
        int pl = b - wblocks;
        if (pl >= planes) return;
        int Wp = W + 2, Hp = H + 2;
        float* p = halo + (size_t)pl * Hp * Wp;
        int per = 2 * Wp + 2 * H;
        for (int i = threadIdx.x; i < per; i += 256) {
            int off;
            if (i < Wp) off = i;
            else if (i < 2 * Wp) off = (Hp - 1) * Wp + (i - Wp);
            else { int j = i - 2 * Wp; int r = j >> 1;
                   off = (r + 1) * Wp + ((j & 1) ? Wp - 1 : 0); }
            p[off] = 0.f;
        }
    }
}

__global__ __launch_bounds__(256)
void pad_x(const float* __restrict__ x, float* __restrict__ xp) {
    int idx = blockIdx.x * 256 + threadIdx.x;
    if (idx >= 6 * 50176) return;
    int c = idx / 50176, hw = idx - c * 50176;
    int h = hw / 224, w = hw - h * 224;
    xp[(c * 226 + h + 1) * 226 + (w + 1)] = x[idx];
}

__global__ __launch_bounds__(256)
void pool_k(const float* __restrict__ in, float* __restrict__ out,
            int planes, int Ho, int Wo, int ipitch, int iplane,
            int opitch, int oplane, int ooff) {
    int idx = blockIdx.x * 256 + threadIdx.x;
    if (idx >= planes * Ho * Wo) return;
    int p = idx / (Ho * Wo), r = idx - p * (Ho * Wo);
    int ho = r / Wo, wo = r - ho * Wo;
    const float* ib = in + (size_t)p * iplane + (size_t)(2 * ho + 1) * ipitch + (2 * wo + 1);
    float m = fmaxf(fmaxf(ib[0], ib[1]), fmaxf(ib[ipitch], ib[ipitch + 1]));
    out[(size_t)p * oplane + (size_t)ho * opitch + wo + ooff] = m;
}

__global__ __launch_bounds__(256)
void chan_minmax(const float* __restrict__ in, float* __restrict__ mn,
                 float* __restrict__ mx, int C, int H, int W) {
    int c = blockIdx.x;
    int Wp = W + 2, plane = (H + 2) * Wp;
    float lmn = INFINITY, lmx = -INFINITY;
    for (int n = 0; n < 2; ++n) {
        const float* p = in + (size_t)(n * C + c) * plane + Wp + 1;
        for (int i = threadIdx.x; i < H * W; i += 256) {
            int h = i / W, w = i - h * W;
            float v = p[h * Wp + w];
            lmn = fminf(lmn, v); lmx = fmaxf(lmx, v);
        }
    }
    __shared__ float smn[4], smx[4];
#pragma unroll
    for (int off = 32; off >= 1; off >>= 1) {
        lmn = fminf(lmn, __shfl_down(lmn, off, 64));
        lmx = fmaxf(lmx, __shfl_down(lmx, off, 64));
    }
    int wave = threadIdx.x >> 6;
    if ((threadIdx.x & 63) == 0) { smn[wave] = lmn; smx[wave] = lmx; }
    __syncthreads();
    if (threadIdx.x == 0) {
        float a = smn[0], b = smx[0];
        for (int i = 1; i < 4; ++i) { a = fminf(a, smn[i]); b = fmaxf(b, smx[i]); }
        mn[c] = a; mx[c] = b;
    }
}

__global__ __launch_bounds__(256)
void quant_apply(float* __restrict__ x, const float* __restrict__ mn,
                 const float* __restrict__ mx, int C, int H, int W) {
    int total = 2 * C * H * W;
    int idx = blockIdx.x * 256 + threadIdx.x;
    if (idx >= total) return;
    int w = idx % W;
    int t = idx / W;
    int h = t % H;
    t /= H;                       // t = n*C + c
    int c = t % C;
    int Wp = W + 2;
    size_t addr = ((size_t)t * (H + 2) + h + 1) * Wp + w + 1;
    float m = mn[c];
    float zd = mx[c] - m;
    float s = 255.f / zd;
    float inv = zd / 255.f;
    float v = x[addr];
    x[addr] = m + rintf((v - m) * s) * inv;
}

// ---------------------------------------------------------------------------
// FC (fp32, HBM-bound on weights): bias-init + split-K atomics + relu
// ---------------------------------------------------------------------------
__global__ __launch_bounds__(256)
void fc_init(const float* __restrict__ b, float* __restrict__ out, int dout) {
    int i = blockIdx.x * blockDim.x + threadIdx.x;
    if (i < 2 * dout) out[i] = b[i % dout];
}

__global__ __launch_bounds__(256)
void fc_splitk(const float* __restrict__ h, const float* __restrict__ w,
               float* __restrict__ out, int din, int dout, int chunk) {
    int o4 = blockIdx.x * blockDim.x + threadIdx.x;
    int o = o4 * 4;
    if (o >= dout) return;
    int d0 = blockIdx.y * chunk;
    int d1 = min(d0 + chunk, din);
    float4 a0 = {0.f, 0.f, 0.f, 0.f};
    float4 a1 = {0.f, 0.f, 0.f, 0.f};
    for (int d = d0; d < d1; ++d) {
        float4 wv = *(const float4*)(w + (size_t)d * dout + o);
        float h0 = h[d];
        float h1 = h[din + d];
        a0.x = fmaf(h0, wv.x, a0.x); a0.y = fmaf(h0, wv.y, a0.y);
        a0.z = fmaf(h0, wv.z, a0.z); a0.w = fmaf(h0, wv.w, a0.w);
        a1.x = fmaf(h1, wv.x, a1.x); a1.y = fmaf(h1, wv.y, a1.y);
        a1.z = fmaf(h1, wv.z, a1.z); a1.w = fmaf(h1, wv.w, a1.w);
    }
    atomicAdd(&out[o + 0], a0.x); atomicAdd(&out[o + 1], a0.y);
    atomicAdd(&out[o + 2], a0.z); atomicAdd(&out[o + 3], a0.w);
    atomicAdd(&out[dout + o + 0], a1.x); atomicAdd(&out[dout + o + 1], a1.y);
    atomicAdd(&out[dout + o + 2], a1.z); atomicAdd(&out[dout + o + 3], a1.w);
}

__global__ __launch_bounds__(256)
void relu_k(float* __restrict__ x, int n) {
    int i = blockIdx.x * blockDim.x + threadIdx.x;
    if (i < n) x[i] = fmaxf(x[i], 0.f);
}

// ---------------------------------------------------------------------------
// Host orchestration
// ---------------------------------------------------------------------------
static void launch_conv(int CIN, const float* in, const ushort* wbf,
                        const float* bias, float* out, int H, int W, int Cout,
                        hipStream_t s) {
    int tw = DIV_UP(W, 8), th = DIV_UP(H, 16);
    dim3 g(tw * th, Cout / 64, 2);
    switch (CIN) {
        case 3:   conv_k1<3>  <<<g, 256, 0, s>>>(in, wbf, bias, out, H, W, tw); break;
        case 64:  conv_k1<64> <<<g, 256, 0, s>>>(in, wbf, bias, out, H, W, tw); break;
        case 128: conv_k1<128><<<g, 256, 0, s>>>(in, wbf, bias, out, H, W, tw); break;
        case 256: conv_k1<256><<<g, 256, 0, s>>>(in, wbf, bias, out, H, W, tw); break;
        case 512: conv_k1<512><<<g, 256, 0, s>>>(in, wbf, bias, out, H, W, tw); break;
    }
}

extern "C" void kernel_launch(void* const* d_in, const int* in_sizes, int n_in,
                              void* d_out, int out_size, void* d_ws, size_t ws_size,
                              hipStream_t stream) {
    const float* x = (const float*)d_in[0];
    const float* cw[13];
    const float* cb[13];
    for (int i = 0; i < 13; ++i) {
        cw[i] = (const float*)d_in[1 + 2 * i];
        cb[i] = (const float*)d_in[2 + 2 * i];
    }
    const float* fw1 = (const float*)d_in[27];
    const float* fb1 = (const float*)d_in[28];
    const float* fw2 = (const float*)d_in[29];
    const float* fb2 = (const float*)d_in[30];
    const float* fw3 = (const float*)d_in[31];
    const float* fb3 = (const float*)d_in[32];

    char* ws = (char*)d_ws;
    const size_t BUF = (size_t)2 * 64 * 226 * 226 * 4;   // 26,150,912 B
    float*  bufA = (float*)ws;
    float*  bufB = (float*)(ws + BUF);
    ushort* wscr = (ushort*)(ws + 2 * BUF);              // 4,718,592 B max
    float*  fc1  = (float*)(ws + 2 * BUF + 4718592);
    float*  fc2  = fc1 + 8192;
    float*  mn   = fc2 + 8192;
    float*  mx   = mn + 64;

    // layer configs: cin, cout, H(=W)
    const int LCI[13] = {3,64, 64,128, 128,256,256, 256,512,512, 512,512,512};
    const int LCO[13] = {64,64, 128,128, 256,256,256, 512,512,512, 512,512,512};
    const int LHW[13] = {224,224, 112,112, 56,56,56, 28,28,28, 14,14,14};

    auto wz = [&](int l, float* dsthalo) {
        int kpad = (LCI[l] == 3) ? 32 : 9 * LCI[l];
        int nblk = LCO[l] * kpad / 8;                    // 16B blocks
        int wblocks = DIV_UP(nblk, 256);
        int planes = 2 * LCO[l];
        wconv_zh<<<wblocks + planes, 256, 0, stream>>>(
            cw[l], wscr, LCI[l], LCO[l], wblocks, dsthalo, planes, LHW[l], LHW[l]);
    };
    auto conv = [&](int l, const float* in, float* out) {
        launch_conv(LCI[l], in, wscr, cb[l], out, LHW[l], LHW[l], LCO[l], stream);
    };
    auto zh = [&](float* buf, int planes, int HW) {
        wconv_zh<<<planes, 256, 0, stream>>>(nullptr, nullptr, 1, 0, 0,
                                             buf, planes, HW, HW);
    };
    auto pool = [&](const float* in, float* out, int planes, int Hin, bool flat) {
        int Ho = Hin / 2;
        int ip = Hin + 2, op = flat ? Ho : Ho + 2;
        pool_k<<<DIV_UP(planes * Ho * Ho, 256), 256, 0, stream>>>(
            in, out, planes, Ho, Ho, ip, ip * ip, op, op * op,
            flat ? 0 : op + 1);
    };

    // input pad (xpad lives at start of bufB; L0 reads it, writes bufA)
    hipMemsetAsync(bufB, 0, (size_t)6 * 226 * 226 * 4, stream);
    pad_x<<<DIV_UP(6 * 50176, 256), 256, 0, stream>>>(x, bufB);

    wz(0, bufA);  conv(0, bufB, bufA);
    wz(1, bufB);  conv(1, bufA, bufB);
    zh(bufA, 128, 112);  pool(bufB, bufA, 128, 224, false);
    chan_minmax<<<64, 256, 0, stream>>>(bufA, mn, mx, 64, 112, 112);
    quant_apply<<<DIV_UP(2 * 64 * 112 * 112, 256), 256, 0, stream>>>(bufA, mn, mx, 64, 112, 112);
    wz(2, bufB);  conv(2, bufA, bufB);
    wz(3, bufA);  conv(3, bufB, bufA);
    zh(bufB, 256, 56);   pool(bufA, bufB, 256, 112, false);
    wz(4, bufA);  conv(4, bufB, bufA);
    wz(5, bufB);  conv(5, bufA, bufB);
    wz(6, bufA);  conv(6, bufB, bufA);
    zh(bufB, 512, 28);   pool(bufA, bufB, 512, 56, false);
    wz(7, bufA);  conv(7, bufB, bufA);
    wz(8, bufB);  conv(8, bufA, bufB);
    wz(9, bufA);  conv(9, bufB, bufA);
    zh(bufB, 1024, 14);  pool(bufA, bufB, 1024, 28, false);
    wz(10, bufA); conv(10, bufB, bufA);
    wz(11, bufB); conv(11, bufA, bufB);
    wz(12, bufA); conv(12, bufB, bufA);
    pool(bufA, bufB, 1024, 14, true);    // flat [2,25088] fp32 at bufB

    auto fc = [&](const float* h, const float* w, const float* b, float* out,
                  int din, int dout, int S, bool relu) {
        fc_init<<<DIV_UP(2 * dout, 256), 256, 0, stream>>>(b, out, dout);
        int chunk = DIV_UP(din, S);
        dim3 g(DIV_UP(dout / 4, 256), S);
        fc_splitk<<<g, 256, 0, stream>>>(h, w, out, din, dout, chunk);
        if (relu) relu_k<<<DIV_UP(2 * dout, 256), 256, 0, stream>>>(out, 2 * dout);
    };
    fc(bufB, fw1, fb1, fc1,           25088, 4096, 64, true);
    fc(fc1,  fw2, fb2, fc2,           4096,  4096, 32, true);
    fc(fc2,  fw3, fb3, (float*)d_out, 4096,  196,  64, false);
}